// Round 5
// baseline (881.329 us; speedup 1.0000x reference)
//
#include <hip/hip_runtime.h>

#define B_ 32
#define N_ 4096
#define D_ 512
#define S_ 8
#define ITERS_ 3

__device__ __forceinline__ float sigmoid_f(float x) {
    return 1.0f / (1.0f + __expf(-x));
}
__device__ __forceinline__ float tanh_f(float x) {
    float e = __expf(2.0f * x);
    return 1.0f - 2.0f / (e + 1.0f);
}

// ---------------------------------------------------------------- slot init (+ LN stats per row)
__global__ __launch_bounds__(256) void k_init(const float* __restrict__ noise,
                                              const float* __restrict__ mu,
                                              const float* __restrict__ sg,
                                              float* __restrict__ slots,
                                              float* __restrict__ stats) {
    int wid = threadIdx.x >> 6, lane = threadIdx.x & 63;
    int row = blockIdx.x * 4 + wid;                       // 0..255
    const float4* nz = (const float4*)(noise + (size_t)row * D_);
    const float4* m4 = (const float4*)(mu + (size_t)(row & 7) * D_);
    const float4* s4 = (const float4*)(sg + (size_t)(row & 7) * D_);
    float4 v0 = nz[lane], v1 = nz[64 + lane];
    float4 a0 = m4[lane], a1 = m4[64 + lane];
    float4 c0 = s4[lane], c1 = s4[64 + lane];
    v0.x = fmaf(c0.x, v0.x, a0.x); v0.y = fmaf(c0.y, v0.y, a0.y);
    v0.z = fmaf(c0.z, v0.z, a0.z); v0.w = fmaf(c0.w, v0.w, a0.w);
    v1.x = fmaf(c1.x, v1.x, a1.x); v1.y = fmaf(c1.y, v1.y, a1.y);
    v1.z = fmaf(c1.z, v1.z, a1.z); v1.w = fmaf(c1.w, v1.w, a1.w);
    float4* o4 = (float4*)(slots + (size_t)row * D_);
    o4[lane] = v0; o4[64 + lane] = v1;
    float s1 = v0.x + v0.y + v0.z + v0.w + v1.x + v1.y + v1.z + v1.w;
    float s2 = v0.x*v0.x; s2 = fmaf(v0.y,v0.y,s2); s2 = fmaf(v0.z,v0.z,s2); s2 = fmaf(v0.w,v0.w,s2);
    s2 = fmaf(v1.x,v1.x,s2); s2 = fmaf(v1.y,v1.y,s2); s2 = fmaf(v1.z,v1.z,s2); s2 = fmaf(v1.w,v1.w,s2);
#pragma unroll
    for (int off = 32; off > 0; off >>= 1) {
        s1 += __shfl_xor(s1, off, 64);
        s2 += __shfl_xor(s2, off, 64);
    }
    if (lane == 0) {
        float mean = s1 * (1.0f / D_);
        float var  = s2 * (1.0f / D_) - mean * mean;
        stats[row * 2]     = mean;
        stats[row * 2 + 1] = rsqrtf(var + 1e-5f);
    }
}

// ---------------------------------------------------------------- small GEMM (prologue only)
// WT=0: C = A[M,K] @ W[K,N]; WT=1: C = A[M,K] @ W[N,K]^T; WT=2: C = A[K,M]^T @ W[K,N]
// LNA=1: A read through LayerNorm
template<int WT, int LNA>
__global__ __launch_bounds__(256) void k_gemm(const float* __restrict__ A,
                                              const float* __restrict__ W,
                                              const float* __restrict__ bias,
                                              float* __restrict__ C,
                                              int M, int N, int K,
                                              const float* __restrict__ stats,
                                              const float* __restrict__ lng,
                                              const float* __restrict__ lnb) {
    __shared__ float As[64][68];
    __shared__ float Ws[64][36];
    int t  = threadIdx.x;
    int bm = blockIdx.y * 64, bn = blockIdx.x * 32;
    int tm = t >> 4, tn = t & 15;
    float acc[4][2] = {{0.f,0.f},{0.f,0.f},{0.f,0.f},{0.f,0.f}};

    for (int kk = 0; kk < K; kk += 64) {
        __syncthreads();
        if (WT == 2) {
#pragma unroll
            for (int r = 0; r < 4; ++r) {
                int idx = t + r * 256;
                int k = idx >> 4, m4 = idx & 15;
                float4 a4 = *(const float4*)(A + (size_t)(kk + k) * M + bm + (m4 << 2));
                *(float4*)&As[k][m4 << 2] = a4;
            }
        } else {
#pragma unroll
            for (int r = 0; r < 4; ++r) {
                int flat = t * 4 + r * 1024;
                int m = flat >> 6, k = flat & 63;
                float4 a4 = *(const float4*)(A + (size_t)(bm + m) * K + kk + k);
                if (LNA) {
                    float mean = stats[(bm + m) * 2];
                    float rs   = stats[(bm + m) * 2 + 1];
                    float4 g4 = *(const float4*)(lng + kk + k);
                    float4 b4 = *(const float4*)(lnb + kk + k);
                    a4.x = fmaf((a4.x - mean) * rs, g4.x, b4.x);
                    a4.y = fmaf((a4.y - mean) * rs, g4.y, b4.y);
                    a4.z = fmaf((a4.z - mean) * rs, g4.z, b4.z);
                    a4.w = fmaf((a4.w - mean) * rs, g4.w, b4.w);
                }
                As[k + 0][m] = a4.x; As[k + 1][m] = a4.y;
                As[k + 2][m] = a4.z; As[k + 3][m] = a4.w;
            }
        }
        if (WT == 1) {
#pragma unroll
            for (int r = 0; r < 2; ++r) {
                int flat = t * 4 + r * 1024;
                int n = flat >> 6, k = flat & 63;
                float4 w4 = *(const float4*)(W + (size_t)(bn + n) * K + kk + k);
                Ws[k + 0][n] = w4.x; Ws[k + 1][n] = w4.y;
                Ws[k + 2][n] = w4.z; Ws[k + 3][n] = w4.w;
            }
        } else {
#pragma unroll
            for (int r = 0; r < 2; ++r) {
                int flat = t * 4 + r * 1024;
                int k = flat >> 5, n = flat & 31;
                float4 w4 = *(const float4*)(W + (size_t)(kk + k) * N + bn + n);
                *(float4*)&Ws[k][n] = w4;
            }
        }
        __syncthreads();
#pragma unroll
        for (int k = 0; k < 64; ++k) {
            float4 a = *(const float4*)&As[k][tm << 2];
            float2 w = *(const float2*)&Ws[k][tn << 1];
            acc[0][0] = fmaf(a.x, w.x, acc[0][0]); acc[0][1] = fmaf(a.x, w.y, acc[0][1]);
            acc[1][0] = fmaf(a.y, w.x, acc[1][0]); acc[1][1] = fmaf(a.y, w.y, acc[1][1]);
            acc[2][0] = fmaf(a.z, w.x, acc[2][0]); acc[2][1] = fmaf(a.z, w.y, acc[2][1]);
            acc[3][0] = fmaf(a.w, w.x, acc[3][0]); acc[3][1] = fmaf(a.w, w.y, acc[3][1]);
        }
    }
#pragma unroll
    for (int i = 0; i < 4; ++i) {
#pragma unroll
        for (int j = 0; j < 2; ++j) {
            int row = bm + (tm << 2) + i;
            int col = bn + (tn << 1) + j;
            float v = acc[i][j];
            if (bias) v += bias[col];
            C[(size_t)row * N + col] = v;
        }
    }
}

// ---------------------------------------------------------------- fused attention (one dispatch / iter)
// per block: build q-tilde/c1/c2 from qk -> phase A (thread-per-row logits/softmax, w->LDS)
//            -> block reduce Av/Tv -> phase B (coalesced P[s][d] partial accumulation)
__global__ __launch_bounds__(256) void k_attn2(const float* __restrict__ x,
                                               const float* __restrict__ qk,
                                               const float* __restrict__ g,
                                               const float* __restrict__ bvec,
                                               float* __restrict__ part,
                                               float* __restrict__ bsum) {
    __shared__ float qts[4096];   // q-tilde, k-major: [(d4)*8 + s] float4s
    __shared__ float ws[2048];    // per-row w[8]
    __shared__ float red[64];
    __shared__ float red2[64];
    __shared__ float c12[16];
    const int nc = blockIdx.x, b = blockIdx.y;
    const int t = threadIdx.x;
    const int w = t >> 6, lane = t & 63;

    // ---- q-prep: qts = g .* qk (k-major), c1[s]=sum(g*qk), c2[s]=sum(b*qk)
    {
        const float4* qk4 = (const float4*)(qk + (size_t)b * 4096);
        const float4* g4 = (const float4*)g;
        const float4* b4 = (const float4*)bvec;
        float c1p[4], c2p[4];
#pragma unroll
        for (int r = 0; r < 4; ++r) {
            int f = t + r * 256;                 // s = f>>7 = (t>>7) + 2r
            float4 v = qk4[f];
            float4 gg = g4[f & 127];
            float4 bb = b4[f & 127];
            float4 qv = make_float4(v.x*gg.x, v.y*gg.y, v.z*gg.z, v.w*gg.w);
            *(float4*)&qts[((f & 127) * 8 + (f >> 7)) * 4] = qv;
            c1p[r] = qv.x + qv.y + qv.z + qv.w;
            c2p[r] = bb.x*v.x + bb.y*v.y + bb.z*v.z + bb.w*v.w;
        }
#pragma unroll
        for (int off = 32; off > 0; off >>= 1) {
#pragma unroll
            for (int r = 0; r < 4; ++r) {
                c1p[r] += __shfl_xor(c1p[r], off, 64);
                c2p[r] += __shfl_xor(c2p[r], off, 64);
            }
        }
        if (lane == 0) {
#pragma unroll
            for (int r = 0; r < 4; ++r) { red[w * 8 + r] = c1p[r]; red2[w * 8 + r] = c2p[r]; }
        }
    }
    __syncthreads();
    if (t < 8) {
        // s even -> waves 0,1 with r=s/2 ; s odd -> waves 2,3 with r=(s-1)/2
        int s = t, wb = (s & 1) ? 2 : 0, r = s >> 1;
        c12[s]     = red[wb * 8 + r]  + red[(wb + 1) * 8 + r];
        c12[8 + s] = red2[wb * 8 + r] + red2[(wb + 1) * 8 + r];
    }
    __syncthreads();

    const float cnorm = 1.0f / (1.0f + 8.0f * 1e-8f);
    const float eadd  = 1e-8f * cnorm;
    float aa[8], wmu[8];
    // ---- phase A: one row per thread
    {
        const float4* rp = (const float4*)(x + ((size_t)b * N_ + nc * 256 + t) * D_);
        float dot[8] = {0.f,0.f,0.f,0.f,0.f,0.f,0.f,0.f};
        float sx = 0.f, sxx = 0.f;
#pragma unroll 2
        for (int k4 = 0; k4 < 128; ++k4) {
            float4 xv = rp[k4];
            sx += xv.x + xv.y + xv.z + xv.w;
            sxx = fmaf(xv.x, xv.x, sxx); sxx = fmaf(xv.y, xv.y, sxx);
            sxx = fmaf(xv.z, xv.z, sxx); sxx = fmaf(xv.w, xv.w, sxx);
#pragma unroll
            for (int s = 0; s < 8; ++s) {
                float4 qv = *(const float4*)&qts[(k4 * 8 + s) * 4];   // LDS broadcast
                dot[s] = fmaf(xv.x, qv.x, dot[s]); dot[s] = fmaf(xv.y, qv.y, dot[s]);
                dot[s] = fmaf(xv.z, qv.z, dot[s]); dot[s] = fmaf(xv.w, qv.w, dot[s]);
            }
        }
        float mean = sx * (1.0f / D_);
        float rs   = rsqrtf(sxx * (1.0f / D_) - mean * mean + 1e-5f);
        float mc   = -rs * mean;
        float l[8];
#pragma unroll
        for (int s = 0; s < 8; ++s)
            l[s] = fmaf(rs, dot[s], fmaf(mc, c12[s], c12[8 + s]));
        float mx = l[0];
#pragma unroll
        for (int s = 1; s < 8; ++s) mx = fmaxf(mx, l[s]);
        float psum = 0.f;
#pragma unroll
        for (int s = 0; s < 8; ++s) { l[s] = __expf(l[s] - mx); psum += l[s]; }
        float ip = cnorm / psum;
        float wv0[8];
#pragma unroll
        for (int s = 0; s < 8; ++s) {
            aa[s]  = fmaf(l[s], ip, eadd);
            wv0[s] = aa[s] * rs;
            wmu[s] = wv0[s] * mean;
        }
        *(float4*)&ws[t * 8]     = make_float4(wv0[0], wv0[1], wv0[2], wv0[3]);
        *(float4*)&ws[t * 8 + 4] = make_float4(wv0[4], wv0[5], wv0[6], wv0[7]);
    }
    // ---- block reduce Av (sum a) and Tv (sum w*mu)
#pragma unroll
    for (int off = 32; off > 0; off >>= 1) {
#pragma unroll
        for (int s = 0; s < 8; ++s) {
            aa[s]  += __shfl_xor(aa[s], off, 64);
            wmu[s] += __shfl_xor(wmu[s], off, 64);
        }
    }
    if (lane == 0) {
#pragma unroll
        for (int s = 0; s < 8; ++s) { red[w * 8 + s] = aa[s]; red2[w * 8 + s] = wmu[s]; }
    }
    __syncthreads();
    if (t < 16) {
        int s = t & 7;
        const float* src = (t < 8) ? red : red2;
        bsum[(size_t)(b * 16 + nc) * 16 + t] = src[s] + src[8 + s] + src[16 + s] + src[24 + s];
    }
    // ---- phase B: coalesced P[s][d] partials (x re-read from L2/L3)
    {
        const int d0 = t * 2;
        const float* xp = x + ((size_t)b * N_ + (size_t)nc * 256) * D_ + d0;
        float P[8][2];
#pragma unroll
        for (int s = 0; s < 8; ++s) { P[s][0] = 0.f; P[s][1] = 0.f; }
#pragma unroll 2
        for (int i = 0; i < 256; ++i) {
            float2 xv = *(const float2*)(xp + (size_t)i * D_);
            float4 w01 = *(const float4*)&ws[i * 8];       // LDS broadcast
            float4 w23 = *(const float4*)&ws[i * 8 + 4];
            P[0][0] = fmaf(w01.x, xv.x, P[0][0]); P[0][1] = fmaf(w01.x, xv.y, P[0][1]);
            P[1][0] = fmaf(w01.y, xv.x, P[1][0]); P[1][1] = fmaf(w01.y, xv.y, P[1][1]);
            P[2][0] = fmaf(w01.z, xv.x, P[2][0]); P[2][1] = fmaf(w01.z, xv.y, P[2][1]);
            P[3][0] = fmaf(w01.w, xv.x, P[3][0]); P[3][1] = fmaf(w01.w, xv.y, P[3][1]);
            P[4][0] = fmaf(w23.x, xv.x, P[4][0]); P[4][1] = fmaf(w23.x, xv.y, P[4][1]);
            P[5][0] = fmaf(w23.y, xv.x, P[5][0]); P[5][1] = fmaf(w23.y, xv.y, P[5][1]);
            P[6][0] = fmaf(w23.z, xv.x, P[6][0]); P[6][1] = fmaf(w23.z, xv.y, P[6][1]);
            P[7][0] = fmaf(w23.w, xv.x, P[7][0]); P[7][1] = fmaf(w23.w, xv.y, P[7][1]);
        }
        float* o = part + (size_t)(b * 16 + nc) * 4096;
#pragma unroll
        for (int s = 0; s < 8; ++s)
            *(float2*)(o + s * 512 + d0) = make_float2(P[s][0], P[s][1]);
    }
}

// ---------------------------------------------------------------- u0 reduce + affine correction
__global__ __launch_bounds__(256) void k_ured(const float* __restrict__ part,
                                              const float* __restrict__ bsum,
                                              const float* __restrict__ g,
                                              const float* __restrict__ bvec,
                                              float* __restrict__ u0) {
    __shared__ float avs[16];
    const int b = blockIdx.x, t = threadIdx.x;
    if (t < 16) {
        float v = 0.f;
#pragma unroll
        for (int nc = 0; nc < 16; ++nc) v += bsum[(size_t)(b * 16 + nc) * 16 + t];
        avs[t] = v;
    }
    __syncthreads();
    const int d0 = t * 2;
    float gg0 = g[d0], gg1 = g[d0 + 1], bb0 = bvec[d0], bb1 = bvec[d0 + 1];
#pragma unroll
    for (int s = 0; s < 8; ++s) {
        float p0 = 0.f, p1 = 0.f;
#pragma unroll
        for (int nc = 0; nc < 16; ++nc) {
            float2 pv = *(const float2*)(part + (size_t)(b * 16 + nc) * 4096 + s * 512 + d0);
            p0 += pv.x; p1 += pv.y;
        }
        float Av = avs[s], Tv = avs[8 + s];
        float* o = u0 + (size_t)(b * 8 + s) * D_ + d0;
        o[0] = fmaf(gg0, p0 - Tv, Av * bb0);
        o[1] = fmaf(gg1, p1 - Tv, Av * bb1);
    }
}

// ---------------------------------------------------------------- gi+gh merged GEMM: gg[256][3072]
// cols 0..1535 = gh = slots @ w_hh^T + b_hh ; cols 1536..3071 = gi = u0 @ Wiv^T + b_ih
__global__ __launch_bounds__(256) void k_gg(const float* __restrict__ slots,
                                            const float* __restrict__ u0,
                                            const float* __restrict__ w_hh,
                                            const float* __restrict__ Wiv,
                                            const float* __restrict__ b_hh,
                                            const float* __restrict__ b_ih,
                                            float* __restrict__ gg) {
    __shared__ float As[64][68];
    __shared__ float Ws[64][36];
    const int t = threadIdx.x;
    const int bx = blockIdx.x;
    const int isGi = (bx >= 48);
    const float* A    = isGi ? u0 : slots;
    const float* W    = isGi ? Wiv : w_hh;
    const float* bias = isGi ? b_ih : b_hh;
    const int bnw = (isGi ? (bx - 48) : bx) * 32;   // col within the 1536-wide W
    const int bnc = bx * 32;                        // col within gg (3072-wide)
    const int bm  = blockIdx.y * 64;
    int tm = t >> 4, tn = t & 15;
    float acc[4][2] = {{0.f,0.f},{0.f,0.f},{0.f,0.f},{0.f,0.f}};

    for (int kk = 0; kk < 512; kk += 64) {
        __syncthreads();
#pragma unroll
        for (int r = 0; r < 4; ++r) {
            int flat = t * 4 + r * 1024;
            int m = flat >> 6, k = flat & 63;
            float4 a4 = *(const float4*)(A + (size_t)(bm + m) * 512 + kk + k);
            As[k + 0][m] = a4.x; As[k + 1][m] = a4.y;
            As[k + 2][m] = a4.z; As[k + 3][m] = a4.w;
        }
#pragma unroll
        for (int r = 0; r < 2; ++r) {
            int flat = t * 4 + r * 1024;
            int n = flat >> 6, k = flat & 63;
            float4 w4 = *(const float4*)(W + (size_t)(bnw + n) * 512 + kk + k);
            Ws[k + 0][n] = w4.x; Ws[k + 1][n] = w4.y;
            Ws[k + 2][n] = w4.z; Ws[k + 3][n] = w4.w;
        }
        __syncthreads();
#pragma unroll
        for (int k = 0; k < 64; ++k) {
            float4 a = *(const float4*)&As[k][tm << 2];
            float2 w = *(const float2*)&Ws[k][tn << 1];
            acc[0][0] = fmaf(a.x, w.x, acc[0][0]); acc[0][1] = fmaf(a.x, w.y, acc[0][1]);
            acc[1][0] = fmaf(a.y, w.x, acc[1][0]); acc[1][1] = fmaf(a.y, w.y, acc[1][1]);
            acc[2][0] = fmaf(a.z, w.x, acc[2][0]); acc[2][1] = fmaf(a.z, w.y, acc[2][1]);
            acc[3][0] = fmaf(a.w, w.x, acc[3][0]); acc[3][1] = fmaf(a.w, w.y, acc[3][1]);
        }
    }
#pragma unroll
    for (int i = 0; i < 4; ++i) {
#pragma unroll
        for (int j = 0; j < 2; ++j) {
            int row = bm + (tm << 2) + i;
            int cw  = bnw + (tn << 1) + j;
            gg[(size_t)row * 3072 + bnc + (tn << 1) + j] = acc[i][j] + bias[cw];
        }
    }
}

// ---------------------------------------------------------------- P2: GRU + MLP + LN + qk_next
__global__ __launch_bounds__(512) void k_p2(const float* __restrict__ gg,
                                            const float* __restrict__ slots,
                                            const float* __restrict__ w1, const float* __restrict__ b1,
                                            const float* __restrict__ w2, const float* __restrict__ b2,
                                            const float* __restrict__ wqkT,
                                            const float* __restrict__ ln_m_g, const float* __restrict__ ln_m_b,
                                            const float* __restrict__ ln_s_g, const float* __restrict__ ln_s_b,
                                            float* __restrict__ dst, float* __restrict__ qkout, int last) {
    __shared__ float s2s[2][512];
    __shared__ float t0s[2][512];
    __shared__ float hs[2][512];
    __shared__ float stat[4];
    const int t = threadIdx.x;
    const int wid = t >> 6, lane = t & 63;
    const int r0 = blockIdx.x * 2;

#pragma unroll
    for (int j = 0; j < 2; ++j) {
        int flat = t + j * 512;
        int r = flat >> 9, d = flat & 511;
        size_t row = r0 + r;
        const float* ghb = gg + row * 3072;
        const float* gib = ghb + 1536;
        float gir = gib[d], giz = gib[d + 512], gin = gib[d + 1024];
        float ghr = ghb[d], ghz = ghb[d + 512], ghn = ghb[d + 1024];
        float rr = sigmoid_f(gir + ghr);
        float zz = sigmoid_f(giz + ghz);
        float nn = tanh_f(fmaf(rr, ghn, gin));
        float sp = slots[row * 512 + d];
        s2s[r][d] = fmaf(1.0f - zz, nn, zz * sp);
    }
    __syncthreads();
    if (wid < 2) {
        const float4* sr = (const float4*)s2s[wid];
        float4 a = sr[lane], bq = sr[64 + lane];
        float s1 = a.x + a.y + a.z + a.w + bq.x + bq.y + bq.z + bq.w;
        float s2 = a.x*a.x; s2 = fmaf(a.y,a.y,s2); s2 = fmaf(a.z,a.z,s2); s2 = fmaf(a.w,a.w,s2);
        s2 = fmaf(bq.x,bq.x,s2); s2 = fmaf(bq.y,bq.y,s2); s2 = fmaf(bq.z,bq.z,s2); s2 = fmaf(bq.w,bq.w,s2);
#pragma unroll
        for (int off = 32; off > 0; off >>= 1) {
            s1 += __shfl_xor(s1, off, 64);
            s2 += __shfl_xor(s2, off, 64);
        }
        if (lane == 0) {
            float mean = s1 * (1.0f / D_);
            float var  = s2 * (1.0f / D_) - mean * mean;
            stat[wid * 2] = mean;
            stat[wid * 2 + 1] = rsqrtf(var + 1e-5f);
        }
    }
    __syncthreads();
#pragma unroll
    for (int j = 0; j < 2; ++j) {
        int flat = t + j * 512;
        int r = flat >> 9, d = flat & 511;
        t0s[r][d] = fmaf((s2s[r][d] - stat[r * 2]) * stat[r * 2 + 1], ln_m_g[d], ln_m_b[d]);
    }
    __syncthreads();
    {
        const int c = t;
        const float4* wr = (const float4*)(w1 + (size_t)c * 512);
        float a0 = 0.f, a1 = 0.f;
#pragma unroll 8
        for (int k4 = 0; k4 < 128; ++k4) {
            float4 w4 = wr[k4];
            float4 q0 = *(const float4*)&t0s[0][k4 << 2];
            float4 q1 = *(const float4*)&t0s[1][k4 << 2];
            a0 = fmaf(q0.x, w4.x, a0); a0 = fmaf(q0.y, w4.y, a0);
            a0 = fmaf(q0.z, w4.z, a0); a0 = fmaf(q0.w, w4.w, a0);
            a1 = fmaf(q1.x, w4.x, a1); a1 = fmaf(q1.y, w4.y, a1);
            a1 = fmaf(q1.z, w4.z, a1); a1 = fmaf(q1.w, w4.w, a1);
        }
        float bc = b1[c];
        hs[0][c] = fmaxf(a0 + bc, 0.f);
        hs[1][c] = fmaxf(a1 + bc, 0.f);
    }
    __syncthreads();
    {
        const int c = t;
        const float4* wr = (const float4*)(w2 + (size_t)c * 512);
        float a0 = 0.f, a1 = 0.f;
#pragma unroll 8
        for (int k4 = 0; k4 < 128; ++k4) {
            float4 w4 = wr[k4];
            float4 q0 = *(const float4*)&hs[0][k4 << 2];
            float4 q1 = *(const float4*)&hs[1][k4 << 2];
            a0 = fmaf(q0.x, w4.x, a0); a0 = fmaf(q0.y, w4.y, a0);
            a0 = fmaf(q0.z, w4.z, a0); a0 = fmaf(q0.w, w4.w, a0);
            a1 = fmaf(q1.x, w4.x, a1); a1 = fmaf(q1.y, w4.y, a1);
            a1 = fmaf(q1.z, w4.z, a1); a1 = fmaf(q1.w, w4.w, a1);
        }
        float bc = b2[c];
        float o0 = s2s[0][c] + a0 + bc;
        float o1 = s2s[1][c] + a1 + bc;
        dst[(size_t)r0 * 512 + c] = o0;
        dst[(size_t)(r0 + 1) * 512 + c] = o1;
        s2s[0][c] = o0;
        s2s[1][c] = o1;
    }
    if (last) return;
    __syncthreads();
    if (wid < 2) {
        const float4* sr = (const float4*)s2s[wid];
        float4 a = sr[lane], bq = sr[64 + lane];
        float s1 = a.x + a.y + a.z + a.w + bq.x + bq.y + bq.z + bq.w;
        float s2 = a.x*a.x; s2 = fmaf(a.y,a.y,s2); s2 = fmaf(a.z,a.z,s2); s2 = fmaf(a.w,a.w,s2);
        s2 = fmaf(bq.x,bq.x,s2); s2 = fmaf(bq.y,bq.y,s2); s2 = fmaf(bq.z,bq.z,s2); s2 = fmaf(bq.w,bq.w,s2);
#pragma unroll
        for (int off = 32; off > 0; off >>= 1) {
            s1 += __shfl_xor(s1, off, 64);
            s2 += __shfl_xor(s2, off, 64);
        }
        if (lane == 0) {
            float mean = s1 * (1.0f / D_);
            float var  = s2 * (1.0f / D_) - mean * mean;
            stat[wid * 2] = mean;
            stat[wid * 2 + 1] = rsqrtf(var + 1e-5f);
        }
    }
    __syncthreads();
#pragma unroll
    for (int j = 0; j < 2; ++j) {
        int flat = t + j * 512;
        int r = flat >> 9, d = flat & 511;
        t0s[r][d] = fmaf((s2s[r][d] - stat[r * 2]) * stat[r * 2 + 1], ln_s_g[d], ln_s_b[d]);
    }
    __syncthreads();
    {
        const int c = t;
        const float4* wr = (const float4*)(wqkT + (size_t)c * 512);
        float a0 = 0.f, a1 = 0.f;
#pragma unroll 8
        for (int k4 = 0; k4 < 128; ++k4) {
            float4 w4 = wr[k4];
            float4 q0 = *(const float4*)&t0s[0][k4 << 2];
            float4 q1 = *(const float4*)&t0s[1][k4 << 2];
            a0 = fmaf(q0.x, w4.x, a0); a0 = fmaf(q0.y, w4.y, a0);
            a0 = fmaf(q0.z, w4.z, a0); a0 = fmaf(q0.w, w4.w, a0);
            a1 = fmaf(q1.x, w4.x, a1); a1 = fmaf(q1.y, w4.y, a1);
            a1 = fmaf(q1.z, w4.z, a1); a1 = fmaf(q1.w, w4.w, a1);
        }
        qkout[(size_t)r0 * 512 + c] = a0;
        qkout[(size_t)(r0 + 1) * 512 + c] = a1;
    }
}

// ---------------------------------------------------------------- launch
extern "C" void kernel_launch(void* const* d_in, const int* in_sizes, int n_in,
                              void* d_out, int out_size, void* d_ws, size_t ws_size,
                              hipStream_t stream) {
    const float* inputs  = (const float*)d_in[0];
    const float* noise   = (const float*)d_in[1];
    const float* mu      = (const float*)d_in[2];
    const float* sg      = (const float*)d_in[3];
    const float* ln_in_g = (const float*)d_in[4];
    const float* ln_in_b = (const float*)d_in[5];
    const float* ln_s_g  = (const float*)d_in[6];
    const float* ln_s_b  = (const float*)d_in[7];
    const float* wq      = (const float*)d_in[8];
    const float* wk      = (const float*)d_in[9];
    const float* wv      = (const float*)d_in[10];
    const float* w_ih    = (const float*)d_in[11];
    const float* w_hh    = (const float*)d_in[12];
    const float* b_ih    = (const float*)d_in[13];
    const float* b_hh    = (const float*)d_in[14];
    const float* ln_m_g  = (const float*)d_in[15];
    const float* ln_m_b  = (const float*)d_in[16];
    const float* w1      = (const float*)d_in[17];
    const float* b1      = (const float*)d_in[18];
    const float* w2      = (const float*)d_in[19];
    const float* b2      = (const float*)d_in[20];

    float* ws = (float*)d_ws;
    const size_t SLOT = (size_t)B_ * S_ * D_;      // 131072
    size_t o = 0;
    float* slots = ws + o; o += SLOT;
    float* qk    = ws + o; o += SLOT;
    float* u0    = ws + o; o += SLOT;
    float* gg    = ws + o; o += (size_t)256 * 3072;       // 786432
    float* Mqk   = ws + o; o += (size_t)D_ * D_;          // 262144
    float* Wiv   = ws + o; o += (size_t)3 * D_ * D_;      // 786432
    float* statsS= ws + o; o += 512;
    float* part  = ws + o; o += (size_t)16 * B_ * 4096;   // 2097152
    float* bsum  = ws + o; o += (size_t)B_ * 16 * 16;     // 8192

    // ---- prologue (4 dispatches)
    k_gemm<2,0><<<dim3(16, 8), 256, 0, stream>>>(wk, wq, nullptr, Mqk,
                                                 512, 512, 512, nullptr, nullptr, nullptr);
    k_gemm<0,0><<<dim3(16, 24), 256, 0, stream>>>(w_ih, wv, nullptr, Wiv,
                                                  1536, 512, 512, nullptr, nullptr, nullptr);
    k_init<<<64, 256, 0, stream>>>(noise, mu, sg, slots, statsS);
    k_gemm<1,1><<<dim3(16, 4), 256, 0, stream>>>(slots, Mqk, nullptr, qk,
                                                 256, 512, 512, statsS, ln_s_g, ln_s_b);

    for (int it = 0; it < ITERS_; ++it) {
        k_attn2<<<dim3(16, B_), 256, 0, stream>>>(inputs, qk, ln_in_g, ln_in_b, part, bsum);
        k_ured<<<B_, 256, 0, stream>>>(part, bsum, ln_in_g, ln_in_b, u0);
        k_gg<<<dim3(96, 4), 256, 0, stream>>>(slots, u0, w_hh, Wiv, b_hh, b_ih, gg);
        int last = (it == ITERS_ - 1);
        float* dst = last ? (float*)d_out : slots;
        k_p2<<<128, 512, 0, stream>>>(gg, slots, w1, b1, w2, b2, Mqk,
                                      ln_m_g, ln_m_b, ln_s_g, ln_s_b, dst, qk, last);
    }
}